// Round 1
// baseline (509.538 us; speedup 1.0000x reference)
//
#include <hip/hip_runtime.h>

#define BATCH   4
#define SEQLEN  4096
#define NHEADS  32
#define PDIM    64
#define NDIM    16
#define CHUNK   64
#define NCHUNK  64   // SEQLEN / CHUNK

// ---------------------------------------------------------------------------
// Kernel 1: per-(b,h,chunk) local states  states[p,n] = sum_t exp(cum63-cum_t) B[t,n] X[t,p]
// also writes per-chunk total A-sum to csum.
// ---------------------------------------------------------------------------
__global__ __launch_bounds__(256) void k_states(
    const float* __restrict__ X, const float* __restrict__ A,
    const float* __restrict__ Bm, float* __restrict__ states,
    float* __restrict__ csum)
{
    const int cc = blockIdx.x, hh = blockIdx.y, bb = blockIdx.z;
    const int tid = threadIdx.x;
    __shared__ float sX[CHUNK][PDIM];
    __shared__ float sB[CHUNK][NDIM];
    __shared__ float sA[CHUNK];
    __shared__ float sCum[CHUNK];
    __shared__ float sDec[CHUNK];
    const int t0 = bb * SEQLEN + cc * CHUNK;

    if (tid < CHUNK) sA[tid] = A[(t0 + tid) * NHEADS + hh];
    for (int e = tid; e < CHUNK * PDIM; e += 256) {
        int t = e >> 6, pp = e & 63;
        sX[t][pp] = X[((t0 + t) * NHEADS + hh) * PDIM + pp];
    }
    for (int e = tid; e < CHUNK * NDIM; e += 256) {
        int t = e >> 4, nn = e & 15;
        sB[t][nn] = Bm[((t0 + t) * NHEADS + hh) * NDIM + nn];
    }
    __syncthreads();
    if (tid < CHUNK) {                 // small serial cumsum, trivial cost
        float s = 0.f;
        for (int j = 0; j <= tid; ++j) s += sA[j];
        sCum[tid] = s;
    }
    __syncthreads();
    const float ctot = sCum[CHUNK - 1];
    if (tid < CHUNK) sDec[tid] = __expf(ctot - sCum[tid]);
    __syncthreads();

    // 1024 outputs [p][n]; thread owns (pp, 4 n's)
    const int pp = tid & 63, ng = tid >> 6;
    float4 acc = make_float4(0.f, 0.f, 0.f, 0.f);
    for (int t = 0; t < CHUNK; ++t) {
        float x = sX[t][pp] * sDec[t];
        float4 b4 = *(const float4*)&sB[t][ng * 4];
        acc.x += x * b4.x; acc.y += x * b4.y;
        acc.z += x * b4.z; acc.w += x * b4.w;
    }
    float* sp = states + ((bb * NHEADS + hh) * NCHUNK + cc) * (PDIM * NDIM)
                       + pp * NDIM + ng * 4;
    *(float4*)sp = acc;
    if (tid == 0) csum[(bb * NHEADS + hh) * NCHUNK + cc] = ctot;
}

// ---------------------------------------------------------------------------
// Kernel 2: in-place sequential scan over chunks per (b,h):
//   S_in(0)=0; for z: out[z]=S_in(z); S_in(z+1)=exp(s_z)*S_in(z)+states_z
// Each thread owns one (p,n) element (independent scans). 4 waves/block,
// 4 blocks per (b,h) slice split over the 1024 elements.
// ---------------------------------------------------------------------------
__global__ __launch_bounds__(256) void k_scan(
    float* __restrict__ states, const float* __restrict__ csum)
{
    const int bh = blockIdx.y;            // 0..127
    const int q  = blockIdx.x;            // 0..3 quarter of the 1024 elements
    const int el = q * 256 + threadIdx.x; // (p,n) flat element
    __shared__ float sE[NCHUNK];
    if (threadIdx.x < NCHUNK) sE[threadIdx.x] = __expf(csum[bh * NCHUNK + threadIdx.x]);
    __syncthreads();
    float S = 0.f;
    float* base = states + (size_t)bh * NCHUNK * (PDIM * NDIM) + el;
    for (int z = 0; z < NCHUNK; ++z) {
        float v = base[z * (PDIM * NDIM)];
        base[z * (PDIM * NDIM)] = S;
        S = sE[z] * S + v;
    }
}

// ---------------------------------------------------------------------------
// Kernel 3: per-(b,h,chunk) output
//   G[t,s] = (t>=s) ? exp(cum_t - cum_s) * dot(C_t, B_s) : 0   (stored [s][t])
//   Y[t,p] = sum_s G[t,s] X[s,p]  +  exp(cum_t) * sum_n C[t,n] S_in[p,n]
// 256 threads, 4x4 register tile per thread for the 64x64x64 GEMM.
// ---------------------------------------------------------------------------
__global__ __launch_bounds__(256) void k_out(
    const float* __restrict__ X, const float* __restrict__ A,
    const float* __restrict__ Bm, const float* __restrict__ Cm,
    const float* __restrict__ states, float* __restrict__ Y)
{
    const int cc = blockIdx.x, hh = blockIdx.y, bb = blockIdx.z;
    const int tid = threadIdx.x;
    __shared__ float sX[CHUNK][PDIM];     // [s][p]
    __shared__ float sG[CHUNK][CHUNK];    // [s][t]
    __shared__ float sB[CHUNK][NDIM];
    __shared__ float sC[CHUNK][NDIM];
    __shared__ float sS2[NDIM][PDIM];     // incoming state, [n][p]
    __shared__ float sA[CHUNK];
    __shared__ float sCum[CHUNK];
    const int t0 = bb * SEQLEN + cc * CHUNK;

    if (tid < CHUNK) sA[tid] = A[(t0 + tid) * NHEADS + hh];
    for (int e = tid; e < CHUNK * PDIM; e += 256) {
        int t = e >> 6, pp = e & 63;
        sX[t][pp] = X[((t0 + t) * NHEADS + hh) * PDIM + pp];
    }
    {
        const int sbase = ((bb * NHEADS + hh) * NCHUNK + cc) * (PDIM * NDIM);
        for (int e = tid; e < CHUNK * NDIM; e += 256) {
            int t = e >> 4, nn = e & 15;
            int gi = ((t0 + t) * NHEADS + hh) * NDIM + nn;
            sB[t][nn] = Bm[gi];
            sC[t][nn] = Cm[gi];
            sS2[nn][t] = states[sbase + e];   // e = p*16+n -> sS2[n][p]
        }
    }
    __syncthreads();
    if (tid < CHUNK) {
        float s = 0.f;
        for (int j = 0; j <= tid; ++j) s += sA[j];
        sCum[tid] = s;
    }
    __syncthreads();

    // ---- build G (4096 entries, 16 per thread, stride-1 writes into [s][t])
    for (int i = 0; i < 16; ++i) {
        int e = tid + 256 * i;
        int s = e >> 6, t = e & 63;
        float g = 0.f;
        if (t >= s) {
            float d = 0.f;
            for (int nn = 0; nn < NDIM; ++nn) d += sC[t][nn] * sB[s][nn];
            g = d * __expf(sCum[t] - sCum[s]);
        }
        sG[s][t] = g;
    }
    __syncthreads();

    // ---- Y_diag: 4x4 register tile; thread (tx,ty): p = tx*4+i, t = ty*4+j
    const int tx = tid & 15, ty = tid >> 4;
    float4 acc[4];
    for (int j = 0; j < 4; ++j) acc[j] = make_float4(0.f, 0.f, 0.f, 0.f);
    for (int s = 0; s < CHUNK; ++s) {
        float4 x4 = *(const float4*)&sX[s][tx * 4];
        float4 g4 = *(const float4*)&sG[s][ty * 4];
        acc[0].x += g4.x * x4.x; acc[0].y += g4.x * x4.y; acc[0].z += g4.x * x4.z; acc[0].w += g4.x * x4.w;
        acc[1].x += g4.y * x4.x; acc[1].y += g4.y * x4.y; acc[1].z += g4.y * x4.z; acc[1].w += g4.y * x4.w;
        acc[2].x += g4.z * x4.x; acc[2].y += g4.z * x4.y; acc[2].z += g4.z * x4.z; acc[2].w += g4.z * x4.w;
        acc[3].x += g4.w * x4.x; acc[3].y += g4.w * x4.y; acc[3].z += g4.w * x4.z; acc[3].w += g4.w * x4.w;
    }

    // ---- Y_off: acc[j] += exp(cum[t_j]) * sum_n C[t_j,n] * S_in[:,n]
    float e0 = __expf(sCum[ty * 4 + 0]);
    float e1 = __expf(sCum[ty * 4 + 1]);
    float e2 = __expf(sCum[ty * 4 + 2]);
    float e3 = __expf(sCum[ty * 4 + 3]);
    for (int nn = 0; nn < NDIM; ++nn) {
        float4 s4 = *(const float4*)&sS2[nn][tx * 4];
        float c0 = sC[ty * 4 + 0][nn] * e0;
        float c1 = sC[ty * 4 + 1][nn] * e1;
        float c2 = sC[ty * 4 + 2][nn] * e2;
        float c3 = sC[ty * 4 + 3][nn] * e3;
        acc[0].x += c0 * s4.x; acc[0].y += c0 * s4.y; acc[0].z += c0 * s4.z; acc[0].w += c0 * s4.w;
        acc[1].x += c1 * s4.x; acc[1].y += c1 * s4.y; acc[1].z += c1 * s4.z; acc[1].w += c1 * s4.w;
        acc[2].x += c2 * s4.x; acc[2].y += c2 * s4.y; acc[2].z += c2 * s4.z; acc[2].w += c2 * s4.w;
        acc[3].x += c3 * s4.x; acc[3].y += c3 * s4.y; acc[3].z += c3 * s4.z; acc[3].w += c3 * s4.w;
    }

    for (int j = 0; j < 4; ++j) {
        int t = ty * 4 + j;
        float* yp = Y + ((size_t)(t0 + t) * NHEADS + hh) * PDIM + tx * 4;
        *(float4*)yp = acc[j];
    }
}

// ---------------------------------------------------------------------------
extern "C" void kernel_launch(void* const* d_in, const int* in_sizes, int n_in,
                              void* d_out, int out_size, void* d_ws, size_t ws_size,
                              hipStream_t stream) {
    const float* X  = (const float*)d_in[0];
    const float* A  = (const float*)d_in[1];
    const float* Bm = (const float*)d_in[2];
    const float* Cm = (const float*)d_in[3];
    float* Y = (float*)d_out;

    // workspace: states [b][h][c][p][n] (33.5 MB) + csum [b][h][c] (32 KB)
    float* states = (float*)d_ws;
    float* csum   = states + (size_t)BATCH * NHEADS * NCHUNK * PDIM * NDIM;

    dim3 grid(NCHUNK, NHEADS, BATCH);
    k_states<<<grid, 256, 0, stream>>>(X, A, Bm, states, csum);
    dim3 gscan(4, BATCH * NHEADS, 1);
    k_scan<<<gscan, 256, 0, stream>>>(states, csum);
    k_out<<<grid, 256, 0, stream>>>(X, A, Bm, Cm, states, Y);
}

// Round 2
// 373.112 us; speedup vs baseline: 1.3656x; 1.3656x over previous
//
#include <hip/hip_runtime.h>

#define BATCH   4
#define SEQLEN  4096
#define NHEADS  32
#define PDIM    64
#define NDIM    16
#define CHUNK   64
#define NCHUNK  64   // SEQLEN / CHUNK

typedef short v8s __attribute__((ext_vector_type(8)));
typedef float v4f __attribute__((ext_vector_type(4)));

__device__ __forceinline__ short f2bf(float f) {
    union { float f; unsigned u; } x; x.f = f;
    unsigned r = (x.u + 0x7FFFu + ((x.u >> 16) & 1u)) >> 16;  // RNE
    return (short)r;
}
__device__ __forceinline__ float bf2f(short s) {
    union { unsigned u; float f; } x; x.u = ((unsigned)(unsigned short)s) << 16;
    return x.f;
}

// ---------------------------------------------------------------------------
// Kernel 1: per-(b,h,chunk) local states (fp32, unchanged from round 1)
// ---------------------------------------------------------------------------
__global__ __launch_bounds__(256) void k_states(
    const float* __restrict__ X, const float* __restrict__ A,
    const float* __restrict__ Bm, float* __restrict__ states,
    float* __restrict__ csum)
{
    const int cc = blockIdx.x, hh = blockIdx.y, bb = blockIdx.z;
    const int tid = threadIdx.x;
    __shared__ float sX[CHUNK][PDIM];
    __shared__ float sB[CHUNK][NDIM];
    __shared__ float sA[CHUNK];
    __shared__ float sCum[CHUNK];
    __shared__ float sDec[CHUNK];
    const int t0 = bb * SEQLEN + cc * CHUNK;

    if (tid < CHUNK) sA[tid] = A[(t0 + tid) * NHEADS + hh];
    for (int e = tid; e < CHUNK * PDIM; e += 256) {
        int t = e >> 6, pp = e & 63;
        sX[t][pp] = X[((size_t)(t0 + t) * NHEADS + hh) * PDIM + pp];
    }
    for (int e = tid; e < CHUNK * NDIM; e += 256) {
        int t = e >> 4, nn = e & 15;
        sB[t][nn] = Bm[((size_t)(t0 + t) * NHEADS + hh) * NDIM + nn];
    }
    __syncthreads();
    if (tid < CHUNK) {
        float s = 0.f;
        for (int j = 0; j <= tid; ++j) s += sA[j];
        sCum[tid] = s;
    }
    __syncthreads();
    const float ctot = sCum[CHUNK - 1];
    if (tid < CHUNK) sDec[tid] = __expf(ctot - sCum[tid]);
    __syncthreads();

    const int pp = tid & 63, ng = tid >> 6;
    float4 acc = make_float4(0.f, 0.f, 0.f, 0.f);
    for (int t = 0; t < CHUNK; ++t) {
        float x = sX[t][pp] * sDec[t];
        float4 b4 = *(const float4*)&sB[t][ng * 4];
        acc.x += x * b4.x; acc.y += x * b4.y;
        acc.z += x * b4.z; acc.w += x * b4.w;
    }
    float* sp = states + ((size_t)(bb * NHEADS + hh) * NCHUNK + cc) * (PDIM * NDIM)
                       + pp * NDIM + ng * 4;
    *(float4*)sp = acc;
    if (tid == 0) csum[(bb * NHEADS + hh) * NCHUNK + cc] = ctot;
}

// ---------------------------------------------------------------------------
// Kernel 2: sequential inter-chunk scan (fp32, unchanged from round 1)
// ---------------------------------------------------------------------------
__global__ __launch_bounds__(256) void k_scan(
    float* __restrict__ states, const float* __restrict__ csum)
{
    const int bh = blockIdx.y;
    const int q  = blockIdx.x;
    const int el = q * 256 + threadIdx.x;
    __shared__ float sE[NCHUNK];
    if (threadIdx.x < NCHUNK) sE[threadIdx.x] = __expf(csum[bh * NCHUNK + threadIdx.x]);
    __syncthreads();
    float S = 0.f;
    float* base = states + (size_t)bh * NCHUNK * (PDIM * NDIM) + el;
    for (int z = 0; z < NCHUNK; ++z) {
        float v = base[z * (PDIM * NDIM)];
        base[z * (PDIM * NDIM)] = S;
        S = sE[z] * S + v;
    }
}

// ---------------------------------------------------------------------------
// Kernel 3: MFMA version.
//   CBT[t][s]   = sum_nn C[t][nn]*B[s][nn]                (mfma, K=16 padded)
//   G[t][s]     = (t>=s) ? exp(cum_t-cum_s)*CBT : 0       (regs -> gF frags)
//   Y[t][p]     = sum_s G[t][s]*X[s][p]                   (mfma, K=64)
//               + sum_nn (e_t*C[t][nn])*S[p][nn]          (mfma, K=16 padded)
// All operands staged in LDS in fragment-linear order: a wave's b128 frag
// read is base + lane*16B -> stride-1, conflict-free.
// ---------------------------------------------------------------------------
__global__ __launch_bounds__(256) void k_out(
    const float* __restrict__ X, const float* __restrict__ A,
    const float* __restrict__ Bm, const float* __restrict__ Cm,
    const float* __restrict__ states, float* __restrict__ Y)
{
    const int cc = blockIdx.x, hh = blockIdx.y, bb = blockIdx.z;
    const int tid = threadIdx.x;
    const int lane = tid & 63, W = tid >> 6;      // wave id 0..3 = t-strip
    const int qq = lane >> 4, nn = lane & 15;
    const int t0 = bb * SEQLEN + cc * CHUNK;

    // gF (G a-frags, 8 KB) overlays sXraw (16.6 KB): sXraw is dead after
    // barrier 2, gF is written after barrier 2.  Total LDS ~37.6 KB -> 4 blk/CU.
    __shared__ __align__(16) char uBuf[CHUNK * (PDIM + 1) * 4];
    float (*sXraw)[PDIM + 1] = (float (*)[PDIM + 1])uBuf;
    short* gF = (short*)uBuf;                     // [W*2+kk][64 lanes][8]
    __shared__ __align__(16) short xF[4096];      // X b-frags [(kk*4+nt)*64+lane][8]
    __shared__ __align__(16) short cF[2048];      // C a-frags [w*64+lane][8] (K=32 pad)
    __shared__ __align__(16) short bF[2048];      // B b-frags [st*64+lane][8] (K=32 pad)
    __shared__ __align__(16) short sF[2048];      // S b-frags [nt*64+lane][8] (K=32 pad)
    __shared__ float sA[CHUNK];
    __shared__ float sCum[CHUNK];

    // ---- stage ----
    if (tid < CHUNK) sA[tid] = A[(t0 + tid) * NHEADS + hh];
    {   // X raw tile (coalesced 256B rows)
        const int sb = tid >> 4, p4 = (tid & 15) * 4;
        for (int i = 0; i < 4; ++i) {
            int s = sb + i * 16;
            const float4 v = *(const float4*)&X[((size_t)(t0 + s) * NHEADS + hh) * PDIM + p4];
            sXraw[s][p4]     = v.x; sXraw[s][p4 + 1] = v.y;
            sXraw[s][p4 + 2] = v.z; sXraw[s][p4 + 3] = v.w;
        }
    }
    {   // C, B, S -> K=32-padded fragment arrays (one float4 each)
        const int r = tid >> 2, nn0 = (tid & 3) * 4;
        const int off = ((r >> 4) * 64 + (nn0 >> 3) * 16 + (r & 15)) * 8 + (nn0 & 7);
        float4 cv = *(const float4*)&Cm[((size_t)(t0 + r) * NHEADS + hh) * NDIM + nn0];
        cF[off] = f2bf(cv.x); cF[off + 1] = f2bf(cv.y);
        cF[off + 2] = f2bf(cv.z); cF[off + 3] = f2bf(cv.w);
        float4 bv = *(const float4*)&Bm[((size_t)(t0 + r) * NHEADS + hh) * NDIM + nn0];
        bF[off] = f2bf(bv.x); bF[off + 1] = f2bf(bv.y);
        bF[off + 2] = f2bf(bv.z); bF[off + 3] = f2bf(bv.w);
        const float* sp = states + ((size_t)(bb * NHEADS + hh) * NCHUNK + cc) * (PDIM * NDIM)
                                 + r * NDIM + nn0;
        float4 sv = *(const float4*)sp;
        sF[off] = f2bf(sv.x); sF[off + 1] = f2bf(sv.y);
        sF[off + 2] = f2bf(sv.z); sF[off + 3] = f2bf(sv.w);
    }
    {   // zero the K=16..31 pad halves (so A-side products vanish)
        const v8s z8 = {0, 0, 0, 0, 0, 0, 0, 0};
        for (int z = tid; z < 384; z += 256) {
            short* base = (z < 128) ? cF : (z < 256) ? bF : sF;
            int idx = z & 127;
            int off = (idx >> 5) * 512 + 256 + (idx & 31) * 8;
            *(v8s*)&base[off] = z8;
        }
    }
    __syncthreads();   // barrier 1

    // ---- cumsum + X -> b-frag layout ----
    if (tid < CHUNK) {
        float s = 0.f;
        for (int j = 0; j <= tid; ++j) s += sA[j];
        sCum[tid] = s;
    }
    for (int c = tid; c < 512; c += 256) {
        int cn = c & 15, cq = (c >> 4) & 3, nt = (c >> 6) & 3, kk = c >> 8;
        int srow = kk * 32 + cq * 8, p = nt * 16 + cn;
        v8s v;
        for (int j = 0; j < 8; ++j) v[j] = f2bf(sXraw[srow + j][p]);
        *(v8s*)&xF[c * 8] = v;
    }
    __syncthreads();   // barrier 2 (sXraw dead; gF may now be written)

    // ---- CBT mfma -> mask/exp -> gF (A-frag layout, overlays sXraw) ----
    const v8s cfrag = *(const v8s*)&cF[(W * 64 + lane) * 8];
    const v4f zero = {0.f, 0.f, 0.f, 0.f};
    for (int st = 0; st < 4; ++st) {
        const int kk = st >> 1, q2 = (st & 1) * 2 + (nn >> 3), j2 = nn & 7;
        if (st <= W) {
            v8s bfrag = *(const v8s*)&bF[(st * 64 + lane) * 8];
            v4f acc = __builtin_amdgcn_mfma_f32_16x16x32_bf16(cfrag, bfrag, zero, 0, 0, 0);
            const int s = st * 16 + nn;
            const float cums = sCum[s];
            for (int r = 0; r < 4; ++r) {
                int t = W * 16 + qq * 4 + r;
                float g = (t >= s) ? acc[r] * __expf(sCum[t] - cums) : 0.f;
                gF[((W * 2 + kk) * 64 + q2 * 16 + qq * 4 + r) * 8 + j2] = f2bf(g);
            }
        } else if (kk == 0 || W >= 2) {   // region will be read -> zero it
            for (int r = 0; r < 4; ++r)
                gF[((W * 2 + kk) * 64 + q2 * 16 + qq * 4 + r) * 8 + j2] = 0;
        }
    }
    // Y_off A-frag: e_t * C (in regs; zeros in pad half stay zero)
    const float et = __expf(sCum[W * 16 + nn]);
    v8s cefrag;
    for (int j = 0; j < 8; ++j) cefrag[j] = f2bf(bf2f(cfrag[j]) * et);
    __syncthreads();   // barrier 3

    // ---- Y = G.X + (e.C).S^T ----
    const v8s ga0 = *(const v8s*)&gF[((W * 2 + 0) * 64 + lane) * 8];
    const bool usekk1 = (W >= 2);
    v8s ga1 = {0, 0, 0, 0, 0, 0, 0, 0};
    if (usekk1) ga1 = *(const v8s*)&gF[((W * 2 + 1) * 64 + lane) * 8];
    v4f acc[4];
    for (int nt = 0; nt < 4; ++nt) {
        v8s sfrag = *(const v8s*)&sF[(nt * 64 + lane) * 8];
        v4f a = __builtin_amdgcn_mfma_f32_16x16x32_bf16(cefrag, sfrag, zero, 0, 0, 0);
        v8s x0 = *(const v8s*)&xF[((0 * 4 + nt) * 64 + lane) * 8];
        a = __builtin_amdgcn_mfma_f32_16x16x32_bf16(ga0, x0, a, 0, 0, 0);
        if (usekk1) {
            v8s x1 = *(const v8s*)&xF[((1 * 4 + nt) * 64 + lane) * 8];
            a = __builtin_amdgcn_mfma_f32_16x16x32_bf16(ga1, x1, a, 0, 0, 0);
        }
        acc[nt] = a;
    }
    for (int r = 0; r < 4; ++r) {
        int t = W * 16 + qq * 4 + r;
        float* yp = Y + ((size_t)(t0 + t) * NHEADS + hh) * PDIM + nn;
        for (int nt = 0; nt < 4; ++nt) yp[nt * 16] = acc[nt][r];
    }
}

// ---------------------------------------------------------------------------
extern "C" void kernel_launch(void* const* d_in, const int* in_sizes, int n_in,
                              void* d_out, int out_size, void* d_ws, size_t ws_size,
                              hipStream_t stream) {
    const float* X  = (const float*)d_in[0];
    const float* A  = (const float*)d_in[1];
    const float* Bm = (const float*)d_in[2];
    const float* Cm = (const float*)d_in[3];
    float* Y = (float*)d_out;

    float* states = (float*)d_ws;
    float* csum   = states + (size_t)BATCH * NHEADS * NCHUNK * PDIM * NDIM;

    dim3 grid(NCHUNK, NHEADS, BATCH);
    k_states<<<grid, 256, 0, stream>>>(X, A, Bm, states, csum);
    dim3 gscan(4, BATCH * NHEADS, 1);
    k_scan<<<gscan, 256, 0, stream>>>(states, csum);
    k_out<<<grid, 256, 0, stream>>>(X, A, Bm, Cm, states, Y);
}

// Round 3
// 334.700 us; speedup vs baseline: 1.5224x; 1.1148x over previous
//
#include <hip/hip_runtime.h>

#define BATCH   4
#define SEQLEN  4096
#define NHEADS  32
#define PDIM    64
#define NDIM    16
#define CHUNK   64
#define NCHUNK  64   // SEQLEN / CHUNK

typedef short v8s __attribute__((ext_vector_type(8)));
typedef float v4f __attribute__((ext_vector_type(4)));

__device__ __forceinline__ short f2bf(float f) {
    union { float f; unsigned u; } x; x.f = f;
    unsigned r = (x.u + 0x7FFFu + ((x.u >> 16) & 1u)) >> 16;  // RNE
    return (short)r;
}
__device__ __forceinline__ float bf2f(short s) {
    union { unsigned u; float f; } x; x.u = ((unsigned)(unsigned short)s) << 16;
    return x.f;
}

// ---------------------------------------------------------------------------
// Kernel 1 (v2, MFMA): states[p,n] = sum_t (dec_t*X[t,p]) * B[t,n]
//   = A-mat (Xw^T, M=p=64, K=t=64) x B-mat (B, K=64, N=n=16)
// Wave W owns p-strip [16W,16W+16): 2 MFMAs (K=32 each).
// ---------------------------------------------------------------------------
__global__ __launch_bounds__(256) void k_states(
    const float* __restrict__ X, const float* __restrict__ A,
    const float* __restrict__ Bm, float* __restrict__ states,
    float* __restrict__ csum)
{
    const int cc = blockIdx.x, hh = blockIdx.y, bb = blockIdx.z;
    const int tid = threadIdx.x;
    const int lane = tid & 63, W = tid >> 6;
    const int t0 = bb * SEQLEN + cc * CHUNK;

    __shared__ __align__(16) float sXraw[CHUNK][PDIM + 1];  // 16.6 KB
    __shared__ __align__(16) short aF[4096];  // Xw A-frags [(pt*2+kk)*64+lane][8]
    __shared__ __align__(16) short bF[1024];  // B  b-frags [kk*64+lane][8]
    __shared__ float sA[CHUNK];
    __shared__ float sCum[CHUNK];
    __shared__ float sDec[CHUNK];

    if (tid < CHUNK) sA[tid] = A[(t0 + tid) * NHEADS + hh];
    {   // X raw tile, coalesced float4
        const int sb = tid >> 4, p4 = (tid & 15) * 4;
        for (int i = 0; i < 4; ++i) {
            int s = sb + i * 16;
            const float4 v = *(const float4*)&X[((size_t)(t0 + s) * NHEADS + hh) * PDIM + p4];
            sXraw[s][p4]     = v.x; sXraw[s][p4 + 1] = v.y;
            sXraw[s][p4 + 2] = v.z; sXraw[s][p4 + 3] = v.w;
        }
    }
    {   // B -> b-frag layout: elem B[t][n] at (( (t>>5)*64 + ((t>>3)&3)*16 + n )*8 + (t&7))
        const int r = tid >> 2, n0 = (tid & 3) * 4;
        float4 bv = *(const float4*)&Bm[((size_t)(t0 + r) * NHEADS + hh) * NDIM + n0];
        const int kk = r >> 5, q = (r >> 3) & 3, j = r & 7;
        const int base = (kk * 64 + q * 16) * 8 + j;
        bF[base + (n0 + 0) * 8] = f2bf(bv.x);
        bF[base + (n0 + 1) * 8] = f2bf(bv.y);
        bF[base + (n0 + 2) * 8] = f2bf(bv.z);
        bF[base + (n0 + 3) * 8] = f2bf(bv.w);
    }
    __syncthreads();
    if (tid < CHUNK) {
        float s = 0.f;
        for (int j = 0; j <= tid; ++j) s += sA[j];
        sCum[tid] = s;
    }
    __syncthreads();
    if (tid < CHUNK) sDec[tid] = __expf(sCum[CHUNK - 1] - sCum[tid]);
    __syncthreads();

    // build Xw A-frags: elem A[m=p&15][k=t] for p-tile pt
    for (int c = tid; c < 512; c += 256) {
        const int m = c & 15, q = (c >> 4) & 3, pt = (c >> 6) & 3, kk = c >> 8;
        const int srow = kk * 32 + q * 8, p = pt * 16 + m;
        v8s v;
        for (int j = 0; j < 8; ++j) v[j] = f2bf(sXraw[srow + j][p] * sDec[srow + j]);
        *(v8s*)&aF[((pt * 2 + kk) * 64 + q * 16 + m) * 8] = v;
    }
    __syncthreads();

    const v4f zero = {0.f, 0.f, 0.f, 0.f};
    v8s a0 = *(const v8s*)&aF[((W * 2 + 0) * 64 + lane) * 8];
    v8s a1 = *(const v8s*)&aF[((W * 2 + 1) * 64 + lane) * 8];
    v8s b0 = *(const v8s*)&bF[(0 * 64 + lane) * 8];
    v8s b1 = *(const v8s*)&bF[(1 * 64 + lane) * 8];
    v4f acc = __builtin_amdgcn_mfma_f32_16x16x32_bf16(a0, b0, zero, 0, 0, 0);
    acc = __builtin_amdgcn_mfma_f32_16x16x32_bf16(a1, b1, acc, 0, 0, 0);

    const int q = lane >> 4, n = lane & 15;
    float* sp = states + ((size_t)(bb * NHEADS + hh) * NCHUNK + cc) * (PDIM * NDIM);
    for (int r = 0; r < 4; ++r)
        sp[(W * 16 + q * 4 + r) * NDIM + n] = acc[r];
    if (tid == 0) csum[(bb * NHEADS + hh) * NCHUNK + cc] = sCum[CHUNK - 1];
}

// ---------------------------------------------------------------------------
// Kernel 2 (v2): batch-register scan. All 64 chunk-values per (p,n) element
// loaded into registers up front (independent, pipelined), serial FMA chain
// in regs, then 64 stores. Removes 64 dependent HBM round-trips.
// ---------------------------------------------------------------------------
__global__ __launch_bounds__(256) void k_scan(
    float* __restrict__ states, const float* __restrict__ csum)
{
    const int bh = blockIdx.y;
    const int el = blockIdx.x * 256 + threadIdx.x;
    __shared__ float sE[NCHUNK];
    if (threadIdx.x < NCHUNK) sE[threadIdx.x] = __expf(csum[bh * NCHUNK + threadIdx.x]);
    __syncthreads();
    float* base = states + (size_t)bh * NCHUNK * (PDIM * NDIM) + el;
    float v[NCHUNK];
#pragma unroll
    for (int z = 0; z < NCHUNK; ++z) v[z] = base[z * (PDIM * NDIM)];
    float S = 0.f;
#pragma unroll
    for (int z = 0; z < NCHUNK; ++z) {
        const float nv = v[z];
        v[z] = S;
        S = sE[z] * S + nv;
    }
#pragma unroll
    for (int z = 0; z < NCHUNK; ++z) base[z * (PDIM * NDIM)] = v[z];
}

// ---------------------------------------------------------------------------
// Kernel 3: MFMA output kernel (unchanged from round 2).
// ---------------------------------------------------------------------------
__global__ __launch_bounds__(256) void k_out(
    const float* __restrict__ X, const float* __restrict__ A,
    const float* __restrict__ Bm, const float* __restrict__ Cm,
    const float* __restrict__ states, float* __restrict__ Y)
{
    const int cc = blockIdx.x, hh = blockIdx.y, bb = blockIdx.z;
    const int tid = threadIdx.x;
    const int lane = tid & 63, W = tid >> 6;
    const int qq = lane >> 4, nn = lane & 15;
    const int t0 = bb * SEQLEN + cc * CHUNK;

    __shared__ __align__(16) char uBuf[CHUNK * (PDIM + 1) * 4];
    float (*sXraw)[PDIM + 1] = (float (*)[PDIM + 1])uBuf;
    short* gF = (short*)uBuf;
    __shared__ __align__(16) short xF[4096];
    __shared__ __align__(16) short cF[2048];
    __shared__ __align__(16) short bF[2048];
    __shared__ __align__(16) short sF[2048];
    __shared__ float sA[CHUNK];
    __shared__ float sCum[CHUNK];

    if (tid < CHUNK) sA[tid] = A[(t0 + tid) * NHEADS + hh];
    {
        const int sb = tid >> 4, p4 = (tid & 15) * 4;
        for (int i = 0; i < 4; ++i) {
            int s = sb + i * 16;
            const float4 v = *(const float4*)&X[((size_t)(t0 + s) * NHEADS + hh) * PDIM + p4];
            sXraw[s][p4]     = v.x; sXraw[s][p4 + 1] = v.y;
            sXraw[s][p4 + 2] = v.z; sXraw[s][p4 + 3] = v.w;
        }
    }
    {
        const int r = tid >> 2, nn0 = (tid & 3) * 4;
        const int off = ((r >> 4) * 64 + (nn0 >> 3) * 16 + (r & 15)) * 8 + (nn0 & 7);
        float4 cv = *(const float4*)&Cm[((size_t)(t0 + r) * NHEADS + hh) * NDIM + nn0];
        cF[off] = f2bf(cv.x); cF[off + 1] = f2bf(cv.y);
        cF[off + 2] = f2bf(cv.z); cF[off + 3] = f2bf(cv.w);
        float4 bv = *(const float4*)&Bm[((size_t)(t0 + r) * NHEADS + hh) * NDIM + nn0];
        bF[off] = f2bf(bv.x); bF[off + 1] = f2bf(bv.y);
        bF[off + 2] = f2bf(bv.z); bF[off + 3] = f2bf(bv.w);
        const float* sp = states + ((size_t)(bb * NHEADS + hh) * NCHUNK + cc) * (PDIM * NDIM)
                                 + r * NDIM + nn0;
        float4 sv = *(const float4*)sp;
        sF[off] = f2bf(sv.x); sF[off + 1] = f2bf(sv.y);
        sF[off + 2] = f2bf(sv.z); sF[off + 3] = f2bf(sv.w);
    }
    {
        const v8s z8 = {0, 0, 0, 0, 0, 0, 0, 0};
        for (int z = tid; z < 384; z += 256) {
            short* base = (z < 128) ? cF : (z < 256) ? bF : sF;
            int idx = z & 127;
            int off = (idx >> 5) * 512 + 256 + (idx & 31) * 8;
            *(v8s*)&base[off] = z8;
        }
    }
    __syncthreads();

    if (tid < CHUNK) {
        float s = 0.f;
        for (int j = 0; j <= tid; ++j) s += sA[j];
        sCum[tid] = s;
    }
    for (int c = tid; c < 512; c += 256) {
        int cn = c & 15, cq = (c >> 4) & 3, nt = (c >> 6) & 3, kk = c >> 8;
        int srow = kk * 32 + cq * 8, p = nt * 16 + cn;
        v8s v;
        for (int j = 0; j < 8; ++j) v[j] = f2bf(sXraw[srow + j][p]);
        *(v8s*)&xF[c * 8] = v;
    }
    __syncthreads();

    const v8s cfrag = *(const v8s*)&cF[(W * 64 + lane) * 8];
    const v4f zero = {0.f, 0.f, 0.f, 0.f};
    for (int st = 0; st < 4; ++st) {
        const int kk = st >> 1, q2 = (st & 1) * 2 + (nn >> 3), j2 = nn & 7;
        if (st <= W) {
            v8s bfrag = *(const v8s*)&bF[(st * 64 + lane) * 8];
            v4f acc = __builtin_amdgcn_mfma_f32_16x16x32_bf16(cfrag, bfrag, zero, 0, 0, 0);
            const int s = st * 16 + nn;
            const float cums = sCum[s];
            for (int r = 0; r < 4; ++r) {
                int t = W * 16 + qq * 4 + r;
                float g = (t >= s) ? acc[r] * __expf(sCum[t] - cums) : 0.f;
                gF[((W * 2 + kk) * 64 + q2 * 16 + qq * 4 + r) * 8 + j2] = f2bf(g);
            }
        } else if (kk == 0 || W >= 2) {
            for (int r = 0; r < 4; ++r)
                gF[((W * 2 + kk) * 64 + q2 * 16 + qq * 4 + r) * 8 + j2] = 0;
        }
    }
    const float et = __expf(sCum[W * 16 + nn]);
    v8s cefrag;
    for (int j = 0; j < 8; ++j) cefrag[j] = f2bf(bf2f(cfrag[j]) * et);
    __syncthreads();

    const v8s ga0 = *(const v8s*)&gF[((W * 2 + 0) * 64 + lane) * 8];
    const bool usekk1 = (W >= 2);
    v8s ga1 = {0, 0, 0, 0, 0, 0, 0, 0};
    if (usekk1) ga1 = *(const v8s*)&gF[((W * 2 + 1) * 64 + lane) * 8];
    v4f acc[4];
    for (int nt = 0; nt < 4; ++nt) {
        v8s sfrag = *(const v8s*)&sF[(nt * 64 + lane) * 8];
        v4f a = __builtin_amdgcn_mfma_f32_16x16x32_bf16(cefrag, sfrag, zero, 0, 0, 0);
        v8s x0 = *(const v8s*)&xF[((0 * 4 + nt) * 64 + lane) * 8];
        a = __builtin_amdgcn_mfma_f32_16x16x32_bf16(ga0, x0, a, 0, 0, 0);
        if (usekk1) {
            v8s x1 = *(const v8s*)&xF[((1 * 4 + nt) * 64 + lane) * 8];
            a = __builtin_amdgcn_mfma_f32_16x16x32_bf16(ga1, x1, a, 0, 0, 0);
        }
        acc[nt] = a;
    }
    for (int r = 0; r < 4; ++r) {
        int t = W * 16 + qq * 4 + r;
        float* yp = Y + ((size_t)(t0 + t) * NHEADS + hh) * PDIM + nn;
        for (int nt = 0; nt < 4; ++nt) yp[nt * 16] = acc[nt][r];
    }
}

// ---------------------------------------------------------------------------
extern "C" void kernel_launch(void* const* d_in, const int* in_sizes, int n_in,
                              void* d_out, int out_size, void* d_ws, size_t ws_size,
                              hipStream_t stream) {
    const float* X  = (const float*)d_in[0];
    const float* A  = (const float*)d_in[1];
    const float* Bm = (const float*)d_in[2];
    const float* Cm = (const float*)d_in[3];
    float* Y = (float*)d_out;

    float* states = (float*)d_ws;
    float* csum   = states + (size_t)BATCH * NHEADS * NCHUNK * PDIM * NDIM;

    dim3 grid(NCHUNK, NHEADS, BATCH);
    k_states<<<grid, 256, 0, stream>>>(X, A, Bm, states, csum);
    dim3 gscan(4, BATCH * NHEADS, 1);
    k_scan<<<gscan, 256, 0, stream>>>(states, csum);
    k_out<<<grid, 256, 0, stream>>>(X, A, Bm, Cm, states, Y);
}